// Round 14
// baseline (31.203 us; speedup 1.0000x reference)
//
#include <hip/hip_runtime.h>
#include <hip/hip_bf16.h>
#include <math.h>

typedef __attribute__((ext_vector_type(8))) short short8;
typedef __attribute__((ext_vector_type(4))) float f32x4;
typedef __attribute__((ext_vector_type(16))) float f32x16;

__device__ __forceinline__ unsigned pkbf2(float lo, float hi) {
    __hip_bfloat162 h = __float22bfloat162_rn(make_float2(lo, hi));
    union { __hip_bfloat162 h; unsigned u; } c;
    c.h = h;
    return c.u;
}

// One fused kernel: 512 blocks (one per batch) x 512 threads (8 waves).
// Wave w owns output cols [w*32, w*32+32). Layer-1 via 16x16x32 MFMA into
// double-buffered LDS slices (R12); obstacles+mask LDS-staged (R13).
// R14: layer-2 uses 32x32x16 MFMA — same LDS traffic, HALF the MFMA
// instructions (64->32 per wave-slice), simpler pool (one col/lane).
// __launch_bounds__(512,2); 64-col/wave geometry needs 200+ regs and always
// spills (R9/R10/R11) — do not revisit.
__global__ __launch_bounds__(512, 2) void actor_kernel(
    const float* __restrict__ obs,  const float* __restrict__ obst,
    const float* __restrict__ eps,  const float* __restrict__ W1,
    const float* __restrict__ b1,   const float* __restrict__ W2,
    const float* __restrict__ b2,   const float* __restrict__ muW,
    const float* __restrict__ mub,  const float* __restrict__ lsW,
    const float* __restrict__ lsb,  float* __restrict__ out)
{
    __shared__ __align__(16) short sA[2][4 * 64 * 64];  // 2 bufs x 32 KB
    __shared__ float sVeh[256];
    __shared__ __align__(8) unsigned sObstPk[256][2];   // bf16 pairs (o0,o1),(o2,o3)
    __shared__ float sMask[256];
    __shared__ float sRed[8][4];

    const int b = blockIdx.x;
    const int t = threadIdx.x;
    const int l = t & 63;
    const int w = t >> 6;          // wave: output cols [w*32, w*32+32)
    const int g = l >> 4;
    const int ln = l & 15;
    const int l5 = l >> 5;
    const int c32 = l & 31;

    const float* ob = obst + b * 1280;

    // ---- prologue staging: threads 0-255 -> sVeh + sMask; 256-511 -> sObstPk ----
    if (t < 256) {
        float a = b1[t];
#pragma unroll
        for (int i = 0; i < 15; ++i) a = fmaf(obs[b * 15 + i], W1[i * 256 + t], a);
        sVeh[t] = a;
        sMask[t] = ob[1024 + t];
    } else {
        int n = t - 256;
        float o0 = ob[n], o1 = ob[256 + n], o2 = ob[512 + n], o3 = ob[768 + n];
        sObstPk[n][0] = pkbf2(o0, o1);
        sObstPk[n][1] = pkbf2(o2, o3);
    }

    // ---- layer-2 B-fragments (32x32x16): frag kt, elem j = W2[kt*16+(l>>5)*8+j][w*32+(l&31)] ----
    short8 bfr[16];
#pragma unroll
    for (int kt = 0; kt < 16; ++kt) {
        const float* p = W2 + (size_t)(kt * 16 + l5 * 8) * 256 + w * 32 + c32;
        union { short8 s; unsigned u[4]; } tv;
        tv.u[0] = pkbf2(p[0 * 256], p[1 * 256]);
        tv.u[1] = pkbf2(p[2 * 256], p[3 * 256]);
        tv.u[2] = pkbf2(p[4 * 256], p[5 * 256]);
        tv.u[3] = pkbf2(p[6 * 256], p[7 * 256]);
        bfr[kt] = tv.s;
    }

    // ---- layer-1 A-fragments (W1obst^T, K=32 with only k<4 nonzero; 16x16x32) ----
    short8 a1[2];
#pragma unroll
    for (int ji = 0; ji < 2; ++ji) {
        union { short8 s; unsigned u[4]; } tv;
        tv.u[0] = 0u; tv.u[1] = 0u; tv.u[2] = 0u; tv.u[3] = 0u;
        if (g == 0) {
            int j = (w * 2 + ji) * 16 + ln;
            tv.u[0] = pkbf2(W1[15 * 256 + j], W1[16 * 256 + j]);
            tv.u[1] = pkbf2(W1[17 * 256 + j], W1[18 * 256 + j]);
        }
        a1[ji] = tv.s;
    }

    const float bbc = b2[w * 32 + c32];   // this lane's single output col bias

    // layer-1 B-fragments for a slice, from LDS (lanes>=16 zero; a1 is zero there)
    short8 bf1[4];
    auto buildB1 = [&](int q) {
#pragma unroll
        for (int nt = 0; nt < 4; ++nt) {
            int n = q * 64 + nt * 16 + ln;
            uint2 o = *reinterpret_cast<const uint2*>(&sObstPk[n][0]);
            union { short8 s; unsigned u[4]; } tv;
            tv.u[0] = o.x; tv.u[1] = o.y; tv.u[2] = 0u; tv.u[3] = 0u;
            bf1[nt] = tv.s;
        }
    };

    // layer-1 of one 64-row slice -> sA[buf] (this wave's 2 j-tiles x 4 n-tiles)
    auto layer1 = [&](int buf) {
        char* base = (char*)&sA[buf][0];
#pragma unroll
        for (int ji = 0; ji < 2; ++ji) {
            int jt = w * 2 + ji;
            int j0 = jt * 16 + g * 4;
            f32x4 bias = *reinterpret_cast<const f32x4*>(&sVeh[j0]);
            unsigned page = (unsigned)(j0 >> 6) * 8192;
            unsigned jbyte = (unsigned)((j0 & 63) * 2);
#pragma unroll
            for (int nt = 0; nt < 4; ++nt) {
                f32x4 d = (f32x4){0.f, 0.f, 0.f, 0.f};
                d = __builtin_amdgcn_mfma_f32_16x16x32_bf16(a1[ji], bf1[nt], d, 0, 0, 0);
                int n = nt * 16 + ln;
                uint2 u;
                u.x = pkbf2(fmaxf(d[0] + bias[0], 0.f), fmaxf(d[1] + bias[1], 0.f));
                u.y = pkbf2(fmaxf(d[2] + bias[2], 0.f), fmaxf(d[3] + bias[3], 0.f));
                unsigned off = page + (unsigned)(n * 128) + (jbyte ^ ((unsigned)((n & 7) << 4)));
                *reinterpret_cast<uint2*>(base + off) = u;
            }
        }
    };

    f32x16 acc32[2];
#pragma unroll
    for (int rt = 0; rt < 2; ++rt)
#pragma unroll
        for (int i = 0; i < 16; ++i) acc32[rt][i] = 0.f;
    float pc = 0.f;                       // raw pooled accumulator (one col/lane)

    __syncthreads();            // staging (sVeh, sObstPk, sMask) ready
    buildB1(0);
    layer1(0);                  // slice 0 -> buf 0
    __syncthreads();            // buf 0 ready

    for (int q = 0; q < 4; ++q) {
        int buf = q & 1;
        // ---- produce next slice into the other buffer (overlaps layer2 below) ----
        if (q < 3) { buildB1(q + 1); layer1(buf ^ 1); }

        // ---- layer 2: full K via 32x32x16; B from registers, A from LDS buf ----
        const char* rbase = (const char*)&sA[buf][0];
#pragma unroll
        for (int kt = 0; kt < 16; ++kt) {
            unsigned page = (unsigned)(kt >> 2) * 8192;
            unsigned kbyte = (unsigned)((kt & 3) * 32 + l5 * 16);
#pragma unroll
            for (int rt = 0; rt < 2; ++rt) {
                int n = rt * 32 + c32;
                unsigned off = page + (unsigned)(n * 128) + (kbyte ^ ((unsigned)((n & 7) << 4)));
                short8 afr = *reinterpret_cast<const short8*>(rbase + off);
                acc32[rt] = __builtin_amdgcn_mfma_f32_32x32x16_bf16(afr, bfr[kt], acc32[rt], 0, 0, 0);
            }
        }

        // ---- masked pool: D row = (reg&3)+8*(reg>>2)+4*(l>>5); col = l&31 ----
        const float* maskq = &sMask[q * 64];
        float pp = 0.f;
#pragma unroll
        for (int rt = 0; rt < 2; ++rt) {
            f32x16 v = acc32[rt];
#pragma unroll
            for (int rg = 0; rg < 4; ++rg) {
                float4 M = *reinterpret_cast<const float4*>(maskq + rt * 32 + rg * 8 + l5 * 4);
                pp = fmaf(M.x, fmaxf(v[rg * 4 + 0] + bbc, 0.f), pp);
                pp = fmaf(M.y, fmaxf(v[rg * 4 + 1] + bbc, 0.f), pp);
                pp = fmaf(M.z, fmaxf(v[rg * 4 + 2] + bbc, 0.f), pp);
                pp = fmaf(M.w, fmaxf(v[rg * 4 + 3] + bbc, 0.f), pp);
            }
#pragma unroll
            for (int i = 0; i < 16; ++i) acc32[rt][i] = 0.f;
        }
        pp += __shfl_xor(pp, 32);          // combine row halves (same col)
        pc += pp;
        if (q < 3) __syncthreads();        // next buf ready / reads drained
    }

    // ---- deferred muW/lsW dot (one col/lane), block reduction, head ----
    int col = w * 32 + c32;
    float2 mw = *reinterpret_cast<const float2*>(muW + col * 2);
    float2 lw = *reinterpret_cast<const float2*>(lsW + col * 2);
    float m0 = pc * mw.x, m1 = pc * mw.y, s0 = pc * lw.x, s1 = pc * lw.y;
#pragma unroll
    for (int off = 1; off < 32; off <<= 1) {
        m0 += __shfl_xor(m0, off);
        m1 += __shfl_xor(m1, off);
        s0 += __shfl_xor(s0, off);
        s1 += __shfl_xor(s1, off);
    }
    if (l == 0) { sRed[w][0] = m0; sRed[w][1] = m1; sRed[w][2] = s0; sRed[w][3] = s1; }
    __syncthreads();
    if (t == 0) {
        float M0 = 0.f, M1 = 0.f, S0 = 0.f, S1 = 0.f;
#pragma unroll
        for (int ww = 0; ww < 8; ++ww) {
            M0 += sRed[ww][0]; M1 += sRed[ww][1];
            S0 += sRed[ww][2]; S1 += sRed[ww][3];
        }
        float mu0 = M0 + mub[0], mu1 = M1 + mub[1];
        float ls0 = fminf(fmaxf(S0 + lsb[0], -20.f), 2.f);
        float ls1 = fminf(fmaxf(S1 + lsb[1], -20.f), 2.f);
        float e0 = eps[b * 2 + 0], e1 = eps[b * 2 + 1];
        float a0 = fmaf(expf(ls0), e0, mu0);
        float a1v = fmaf(expf(ls1), e1, mu1);
        float logp = -0.5f * (e0 * e0 + e1 * e1) - (ls0 + ls1) - 1.8378770664093453f;
        float x0 = -2.f * a0, x1 = -2.f * a1v;
        float sp0 = fmaxf(x0, 0.f) + log1pf(expf(-fabsf(x0)));
        float sp1 = fmaxf(x1, 0.f) + log1pf(expf(-fabsf(x1)));
        logp -= 2.f * (0.6931471805599453f - a0 - sp0);
        logp -= 2.f * (0.6931471805599453f - a1v - sp1);
        out[b * 2 + 0] = tanhf(a0);
        out[b * 2 + 1] = tanhf(a1v);
        out[1024 + b] = logp;
    }
}

extern "C" void kernel_launch(void* const* d_in, const int* in_sizes, int n_in,
                              void* d_out, int out_size, void* d_ws, size_t ws_size,
                              hipStream_t stream) {
    const float* obs  = (const float*)d_in[0];
    const float* obst = (const float*)d_in[1];
    const float* eps  = (const float*)d_in[2];
    const float* W1   = (const float*)d_in[3];
    const float* b1   = (const float*)d_in[4];
    const float* W2   = (const float*)d_in[5];
    const float* b2   = (const float*)d_in[6];
    const float* muW  = (const float*)d_in[7];
    const float* mub  = (const float*)d_in[8];
    const float* lsW  = (const float*)d_in[9];
    const float* lsb  = (const float*)d_in[10];
    float* out = (float*)d_out;

    actor_kernel<<<512, 512, 0, stream>>>(obs, obst, eps, W1, b1, W2, b2,
                                          muW, mub, lsW, lsb, out);
}